// Round 1
// baseline (432.326 us; speedup 1.0000x reference)
//
#include <hip/hip_runtime.h>
#include <math.h>

// Problem constants (fixed by reference setup)
#define N_SRC 8192
#define M_TGT 16384
#define DDIM  64
#define REG_P 0.05f

// Tiling config for the main kernel
#define ROWS      32            // source rows per block
#define CCHUNK    128           // target cols staged per iteration
#define TPAD      68            // padded target row stride (floats), 272B (16B-aligned)
#define HALVES    2             // column split across blocks (for 2 blocks/CU occupancy)
#define COLS_HALF (M_TGT / HALVES)   // 8192
#define NCHUNK    (COLS_HALF / CCHUNK) // 64

// Workspace layout (float offsets)
#define WS_SUMSQT 0
#define WS_SUMPSI 1
#define WS_SQT    64
#define WS_M      (WS_SQT + M_TGT)            // [HALVES][N_SRC]
#define WS_L      (WS_M + HALVES * N_SRC)     // [HALVES][N_SRC]
#define WS_A      (WS_L + HALVES * N_SRC)     // [N_SRC]

// Kernel 1: per-target squared norms + global sums of sq_t and psi.
__global__ __launch_bounds__(256) void k1_target(const float* __restrict__ tgt,
                                                 const float* __restrict__ psi,
                                                 float* __restrict__ ws) {
    const int j = blockIdx.x * 256 + threadIdx.x;   // grid = M/256 = 64
    const float4* row = (const float4*)(tgt + (size_t)j * DDIM);
    float s = 0.f;
#pragma unroll
    for (int k = 0; k < DDIM / 4; ++k) {
        float4 v = row[k];
        s += v.x * v.x + v.y * v.y + v.z * v.z + v.w * v.w;
    }
    ws[WS_SQT + j] = s;
    float p = psi[j];

    __shared__ float red0[256];
    __shared__ float red1[256];
    red0[threadIdx.x] = s;
    red1[threadIdx.x] = p;
    __syncthreads();
    for (int off = 128; off > 0; off >>= 1) {
        if (threadIdx.x < off) {
            red0[threadIdx.x] += red0[threadIdx.x + off];
            red1[threadIdx.x] += red1[threadIdx.x + off];
        }
        __syncthreads();
    }
    if (threadIdx.x == 0) {
        atomicAdd(&ws[WS_SUMSQT], red0[0]);
        atomicAdd(&ws[WS_SUMPSI], red1[0]);
    }
}

// Kernel 2: fused fp32 GEMM (source x target^T) + online logsumexp per row.
// Grid = (N/ROWS) * HALVES = 512 blocks of 256 threads.
__global__ __launch_bounds__(256, 2) void k2_main(const float* __restrict__ src,
                                                  const float* __restrict__ tgt,
                                                  const float* __restrict__ psi,
                                                  float* __restrict__ ws) {
    const int tid    = threadIdx.x;
    const int rowblk = blockIdx.x >> 1;
    const int half   = blockIdx.x & 1;
    const int row0   = rowblk * ROWS;
    const int col0   = half * COLS_HALF;

    __shared__ float s_src[ROWS][DDIM];     // 8 KB
    __shared__ float s_tgt[CCHUNK][TPAD];   // 34 KB (padded: 4-way worst conflict)
    __shared__ float s_bias[CCHUNK];
    __shared__ float s_A[ROWS];
    __shared__ float s_red[ROWS][8];

    const float sum_sqt = ws[WS_SUMSQT];
    const float inv_cn  = (float)M_TGT / sum_sqt;   // 1 / mean(sq_t)
    const float inv_reg = 1.0f / REG_P;
    const float alpha   = 2.0f * inv_reg * inv_cn;
    const float log_nu  = -logf((float)M_TGT);

    // Stage source tile: ROWS*DDIM = 2048 floats = 512 float4, 2 per thread.
    {
        const float4* g = (const float4*)(src + (size_t)row0 * DDIM);
#pragma unroll
        for (int k = 0; k < 2; ++k) {
            int f  = tid + k * 256;
            int r  = f >> 4;
            int dd = (f & 15) << 2;
            *(float4*)&s_src[r][dd] = g[f];
        }
    }
    __syncthreads();

    // Per-row A_i = -sq_s * inv_cn * inv_reg + log_nu
    {
        int r = tid >> 3, part = tid & 7;
        float s = 0.f;
#pragma unroll
        for (int d = 0; d < 8; ++d) {
            float v = s_src[r][part * 8 + d];
            s += v * v;
        }
        s_red[r][part] = s;
    }
    __syncthreads();
    if (tid < ROWS) {
        float s = 0.f;
#pragma unroll
        for (int k = 0; k < 8; ++k) s += s_red[tid][k];
        s_A[tid] = -s * inv_cn * inv_reg + log_nu;
    }

    const int tx = tid & 31;   // column lane
    const int ty = tid >> 5;   // 0..7 row group
    const int r0 = ty * 4;

    float m[4], l[4];
#pragma unroll
    for (int r = 0; r < 4; ++r) { m[r] = -3.0e38f; l[r] = 0.f; }

    for (int c = 0; c < NCHUNK; ++c) {
        const int j0 = col0 + c * CCHUNK;
        __syncthreads();  // protect s_tgt/s_bias from previous iteration readers
        {
            const float4* g = (const float4*)(tgt + (size_t)j0 * DDIM);
#pragma unroll
            for (int k = 0; k < 8; ++k) {
                int f  = tid + k * 256;
                int r  = f >> 4;
                int dd = (f & 15) << 2;
                *(float4*)&s_tgt[r][dd] = g[f];
            }
        }
        if (tid < CCHUNK) {
            int j = j0 + tid;
            s_bias[tid] = (psi[j] - ws[WS_SQT + j] * inv_cn) * inv_reg;
        }
        __syncthreads();

        float acc[4][4];
#pragma unroll
        for (int r = 0; r < 4; ++r)
#pragma unroll
            for (int q = 0; q < 4; ++q) acc[r][q] = 0.f;

#pragma unroll
        for (int dc = 0; dc < DDIM / 4; ++dc) {
            float4 sv[4], tv[4];
#pragma unroll
            for (int r = 0; r < 4; ++r) sv[r] = *(const float4*)&s_src[r0 + r][dc * 4];
#pragma unroll
            for (int q = 0; q < 4; ++q) tv[q] = *(const float4*)&s_tgt[q * 32 + tx][dc * 4];
#pragma unroll
            for (int r = 0; r < 4; ++r)
#pragma unroll
                for (int q = 0; q < 4; ++q)
                    acc[r][q] += sv[r].x * tv[q].x + sv[r].y * tv[q].y +
                                 sv[r].z * tv[q].z + sv[r].w * tv[q].w;
        }

        // Online logsumexp update (4 cols at a time per row)
#pragma unroll
        for (int r = 0; r < 4; ++r) {
            float s0 = alpha * acc[r][0] + s_bias[0 * 32 + tx];
            float s1 = alpha * acc[r][1] + s_bias[1 * 32 + tx];
            float s2 = alpha * acc[r][2] + s_bias[2 * 32 + tx];
            float s3 = alpha * acc[r][3] + s_bias[3 * 32 + tx];
            float m4 = fmaxf(fmaxf(s0, s1), fmaxf(s2, s3));
            float mn = fmaxf(m[r], m4);
            l[r] = l[r] * __expf(m[r] - mn) +
                   (__expf(s0 - mn) + __expf(s1 - mn) + __expf(s2 - mn) + __expf(s3 - mn));
            m[r] = mn;
        }
    }

    // Combine (m,l) across the 32 tx lanes (xor masks stay within the half-wave)
#pragma unroll
    for (int r = 0; r < 4; ++r) {
#pragma unroll
        for (int off = 1; off < 32; off <<= 1) {
            float mo = __shfl_xor(m[r], off, 64);
            float lo = __shfl_xor(l[r], off, 64);
            float mn = fmaxf(m[r], mo);
            l[r] = l[r] * __expf(m[r] - mn) + lo * __expf(mo - mn);
            m[r] = mn;
        }
    }
    if (tx == 0) {
#pragma unroll
        for (int r = 0; r < 4; ++r) {
            int row = row0 + r0 + r;
            ws[WS_M + half * N_SRC + row] = m[r];
            ws[WS_L + half * N_SRC + row] = l[r];
            if (half == 0) ws[WS_A + row] = s_A[r0 + r];
        }
    }
}

// Kernel 3: combine column halves, reduce rows, emit scalar.
__global__ __launch_bounds__(256) void k3_final(const float* __restrict__ ws,
                                                float* __restrict__ out) {
    const int tid = threadIdx.x;
    float acc = 0.f;
    for (int i = tid; i < N_SRC; i += 256) {
        float m0 = ws[WS_M + i],         l0 = ws[WS_L + i];
        float m1 = ws[WS_M + N_SRC + i], l1 = ws[WS_L + N_SRC + i];
        float A  = ws[WS_A + i];
        float mn = fmaxf(m0, m1);
        float lt = l0 * __expf(m0 - mn) + l1 * __expf(m1 - mn);
        float lse = A + mn + logf(lt);
        acc += -REG_P * lse;
    }
    __shared__ float red[256];
    red[tid] = acc;
    __syncthreads();
    for (int off = 128; off > 0; off >>= 1) {
        if (tid < off) red[tid] += red[tid + off];
        __syncthreads();
    }
    if (tid == 0) {
        out[0] = red[0] / (float)N_SRC + ws[WS_SUMPSI] / (float)M_TGT;
    }
}

extern "C" void kernel_launch(void* const* d_in, const int* in_sizes, int n_in,
                              void* d_out, int out_size, void* d_ws, size_t ws_size,
                              hipStream_t stream) {
    const float* src = (const float*)d_in[0];   // [N, D]
    const float* tgt = (const float*)d_in[1];   // [M, D]
    const float* psi = (const float*)d_in[2];   // [M]
    float* ws  = (float*)d_ws;
    float* out = (float*)d_out;

    // Zero the accumulator header (ws is poisoned 0xAA before every launch).
    hipMemsetAsync(d_ws, 0, 64 * sizeof(float), stream);

    k1_target<<<M_TGT / 256, 256, 0, stream>>>(tgt, psi, ws);
    k2_main<<<(N_SRC / ROWS) * HALVES, 256, 0, stream>>>(src, tgt, psi, ws);
    k3_final<<<1, 256, 0, stream>>>(ws, out);
}

// Round 2
// 119.022 us; speedup vs baseline: 3.6323x; 3.6323x over previous
//
#include <hip/hip_runtime.h>
#include <math.h>
#include <stdint.h>

#define N_SRC 8192
#define M_TGT 16384
#define DDIM  64
#define REG_P 0.05f
#define LOG2E 1.44269504088896340736f
#define LN2   0.69314718055994530942f

// k2 tiling: 64 src rows per block, column space split 8 ways -> 1024 blocks (4/CU)
#define QSPLIT 8
#define CHUNKS (M_TGT / QSPLIT / 128)   // 16 chunks of 128 cols per block

typedef __attribute__((ext_vector_type(8))) short short8;
typedef __attribute__((ext_vector_type(4))) float f32x4;

// Workspace byte offsets
#define OFF_TGT  0u                         // staged tgt bf16, frag-order: 2 MB
#define OFF_SRC  (2u << 20)                 // staged src bf16, frag-order: 1 MB
#define OFF_SQT  (3u << 20)                 // sq_t[M]: 64 KB
#define OFF_BIAS ((3u << 20) + 65536u)      // bias2[M] (exp2 domain): 64 KB
#define OFF_A    ((3u << 20) + 131072u)     // A[N]: 32 KB
#define OFF_L    ((3u << 20) + 163840u)     // l[N] partial sums: 32 KB (memset 0)
#define OFF_SUMS ((3u << 20) + 196608u)     // [0]=sum sq_t, [1]=sum psi (memset 0)

__device__ __forceinline__ unsigned short f2bf(float f) {   // RNE fp32->bf16
    unsigned u = __float_as_uint(f);
    u += 0x7fffu + ((u >> 16) & 1u);
    return (unsigned short)(u >> 16);
}

__device__ __forceinline__ float fast_exp2(float x) {
#if __has_builtin(__builtin_amdgcn_exp2f)
    return __builtin_amdgcn_exp2f(x);
#else
    return exp2f(x);
#endif
}

__device__ __forceinline__ void gload_lds16(const void* g, void* l) {
    __builtin_amdgcn_global_load_lds(
        (const __attribute__((address_space(1))) void*)g,
        (__attribute__((address_space(3))) void*)l, 16, 0, 0);
}

// k1a: tgt -> bf16 staged in B-frag order; sq_t[j]; global sums of sq_t, psi.
// 8 threads per row, each owns one 16B staging unit (8 bf16).
__global__ __launch_bounds__(256) void k1a_tgt(const float* __restrict__ tgt,
                                               const float* __restrict__ psi,
                                               char* __restrict__ ws) {
    const int tid = threadIdx.x;
    const int j   = blockIdx.x * 32 + (tid >> 3);
    const int d0  = (tid & 7) << 3;
    const float* rp = tgt + (size_t)j * DDIM + d0;
    float4 v0 = *(const float4*)rp;
    float4 v1 = *(const float4*)(rp + 4);
    short8 pk;
    pk[0]=(short)f2bf(v0.x); pk[1]=(short)f2bf(v0.y); pk[2]=(short)f2bf(v0.z); pk[3]=(short)f2bf(v0.w);
    pk[4]=(short)f2bf(v1.x); pk[5]=(short)f2bf(v1.y); pk[6]=(short)f2bf(v1.z); pk[7]=(short)f2bf(v1.w);
    const int c  = j >> 7, t = (j >> 4) & 7, lo = j & 15;
    const int kk = d0 >> 5, hi = (d0 >> 3) & 3;
    // unit index = (chunk*16 + tile*2 + kk)*64 + lane, lane = hi*16+lo
    *(short8*)(ws + OFF_TGT + ((size_t)((c * 16 + t * 2 + kk) * 64 + hi * 16 + lo)) * 16) = pk;

    float sq = v0.x*v0.x + v0.y*v0.y + v0.z*v0.z + v0.w*v0.w
             + v1.x*v1.x + v1.y*v1.y + v1.z*v1.z + v1.w*v1.w;
    float rs = sq;
    rs += __shfl_xor(rs, 1); rs += __shfl_xor(rs, 2); rs += __shfl_xor(rs, 4);
    if ((tid & 7) == 0) ((float*)(ws + OFF_SQT))[j] = rs;
    float ps = ((tid & 7) == 0) ? psi[j] : 0.f;

    __shared__ float r0[256], r1[256];
    r0[tid] = sq; r1[tid] = ps;
    __syncthreads();
    for (int off = 128; off > 0; off >>= 1) {
        if (tid < off) { r0[tid] += r0[tid + off]; r1[tid] += r1[tid + off]; }
        __syncthreads();
    }
    if (tid == 0) {
        float* sums = (float*)(ws + OFF_SUMS);
        atomicAdd(&sums[0], r0[0]);
        atomicAdd(&sums[1], r1[0]);
    }
}

// k1b: blocks 0..255 stage src (A-frag order) + A_i; blocks 256..319 compute bias2[j].
__global__ __launch_bounds__(256) void k1b_src(const float* __restrict__ src,
                                               const float* __restrict__ psi,
                                               char* __restrict__ ws) {
    const int tid = threadIdx.x;
    const float* sums = (const float*)(ws + OFF_SUMS);
    const float inv_cn = (float)M_TGT / sums[0];
    if (blockIdx.x < 256) {
        const int i  = blockIdx.x * 32 + (tid >> 3);
        const int d0 = (tid & 7) << 3;
        const float* rp = src + (size_t)i * DDIM + d0;
        float4 v0 = *(const float4*)rp;
        float4 v1 = *(const float4*)(rp + 4);
        short8 pk;
        pk[0]=(short)f2bf(v0.x); pk[1]=(short)f2bf(v0.y); pk[2]=(short)f2bf(v0.z); pk[3]=(short)f2bf(v0.w);
        pk[4]=(short)f2bf(v1.x); pk[5]=(short)f2bf(v1.y); pk[6]=(short)f2bf(v1.z); pk[7]=(short)f2bf(v1.w);
        const int g = i >> 4, lo = i & 15;
        const int kk = d0 >> 5, hi = (d0 >> 3) & 3;
        *(short8*)(ws + OFF_SRC + ((size_t)((g * 2 + kk) * 64 + hi * 16 + lo)) * 16) = pk;
        float sq = v0.x*v0.x + v0.y*v0.y + v0.z*v0.z + v0.w*v0.w
                 + v1.x*v1.x + v1.y*v1.y + v1.z*v1.z + v1.w*v1.w;
        float rs = sq;
        rs += __shfl_xor(rs, 1); rs += __shfl_xor(rs, 2); rs += __shfl_xor(rs, 4);
        if ((tid & 7) == 0)
            ((float*)(ws + OFF_A))[i] = -rs * inv_cn * (1.0f / REG_P) - logf((float)M_TGT);
    } else {
        const int j = (blockIdx.x - 256) * 256 + tid;
        const float sqt = ((const float*)(ws + OFF_SQT))[j];
        ((float*)(ws + OFF_BIAS))[j] = (psi[j] - sqt * inv_cn) * (1.0f / REG_P) * LOG2E;
    }
}

// k2: MFMA GEMM fused with sum-exp2. 64 rows x 2048-col slice per block.
__global__ __launch_bounds__(256, 4) void k2_main(char* __restrict__ ws) {
    const int tid  = threadIdx.x;
    const int lane = tid & 63;
    const int w    = tid >> 6;
    const int rowblk = blockIdx.x >> 3;
    const int q      = blockIdx.x & (QSPLIT - 1);
    const int row0   = rowblk * 64;

    __shared__ __align__(16) char s_buf[2][16384];
    __shared__ float s_bias[2][128];

    const float* sums = (const float*)(ws + OFF_SUMS);
    const float inv_cn = (float)M_TGT / sums[0];
    const float alpha2 = 2.0f * inv_cn * (1.0f / REG_P) * LOG2E;

    // A-fragments: 4 row-groups x 2 K-steps, resident in registers all kernel.
    const short8* __restrict__ srcst = (const short8*)(ws + OFF_SRC);
    short8 Af[4][2];
#pragma unroll
    for (int g = 0; g < 4; ++g)
#pragma unroll
        for (int kk = 0; kk < 2; ++kk)
            Af[g][kk] = srcst[((row0 >> 4) + g) * 128 + kk * 64 + lane];

    const float* __restrict__ biasArr = (const float*)(ws + OFF_BIAS);

    float lsum[4][4];
#pragma unroll
    for (int g = 0; g < 4; ++g)
#pragma unroll
        for (int r = 0; r < 4; ++r) lsum[g][r] = 0.f;

    // Prologue: stage chunk 0
    {
        const int gc = q * CHUNKS;
        const char* gp = ws + OFF_TGT + (size_t)gc * 16384;
#pragma unroll
        for (int r = 0; r < 4; ++r)
            gload_lds16(gp + (r * 256 + tid) * 16, &s_buf[0][(r * 256 + (tid & ~63)) * 16]);
        if (tid < 128) s_bias[0][tid] = biasArr[gc * 128 + tid];
    }

    for (int c = 0; c < CHUNKS; ++c) {
        __syncthreads();   // drains chunk-c staging; all waves done reading buf[(c+1)&1]
        if (c + 1 < CHUNKS) {
            const int gc = q * CHUNKS + c + 1;
            const char* gp = ws + OFF_TGT + (size_t)gc * 16384;
            const int nb = (c + 1) & 1;
#pragma unroll
            for (int r = 0; r < 4; ++r)
                gload_lds16(gp + (r * 256 + tid) * 16, &s_buf[nb][(r * 256 + (tid & ~63)) * 16]);
            if (tid < 128) s_bias[nb][tid] = biasArr[gc * 128 + tid];
        }
        const char* buf = s_buf[c & 1];
        const float* bias = s_bias[c & 1];
#pragma unroll
        for (int s = 0; s < 2; ++s) {
            const int t = w + s * 4;   // this wave's col-tile within the 128-col chunk
            short8 B0 = *(const short8*)(buf + ((t * 2 + 0) * 64 + lane) * 16);
            short8 B1 = *(const short8*)(buf + ((t * 2 + 1) * 64 + lane) * 16);
            const float bt = bias[t * 16 + (lane & 15)];
            f32x4 acc[4];
#pragma unroll
            for (int g = 0; g < 4; ++g) {
                f32x4 a = {0.f, 0.f, 0.f, 0.f};
                a = __builtin_amdgcn_mfma_f32_16x16x32_bf16(Af[g][0], B0, a, 0, 0, 0);
                a = __builtin_amdgcn_mfma_f32_16x16x32_bf16(Af[g][1], B1, a, 0, 0, 0);
                acc[g] = a;
            }
#pragma unroll
            for (int g = 0; g < 4; ++g)
#pragma unroll
                for (int r = 0; r < 4; ++r)
                    lsum[g][r] += fast_exp2(fmaf(alpha2, acc[g][r], bt));
        }
    }

    // Reduce partial sum-exp over the 16 lanes sharing a row, then atomic-combine.
    float* ws_l = (float*)(ws + OFF_L);
#pragma unroll
    for (int g = 0; g < 4; ++g)
#pragma unroll
        for (int r = 0; r < 4; ++r) {
            float v = lsum[g][r];
            v += __shfl_xor(v, 1); v += __shfl_xor(v, 2);
            v += __shfl_xor(v, 4); v += __shfl_xor(v, 8);
            if ((lane & 15) == 0)
                atomicAdd(&ws_l[row0 + g * 16 + (lane >> 4) * 4 + r], v);
        }
}

// k3: lse_i = A_i + ln2*log2(l_i); out = mean(-reg*lse) + mean(psi)
__global__ __launch_bounds__(256) void k3_final(const char* __restrict__ ws,
                                                float* __restrict__ out) {
    const int tid = threadIdx.x;
    const float* A = (const float*)(ws + OFF_A);
    const float* L = (const float*)(ws + OFF_L);
    const float* sums = (const float*)(ws + OFF_SUMS);
    float acc = 0.f;
    for (int i = tid; i < N_SRC; i += 256)
        acc += -REG_P * (A[i] + LN2 * __log2f(L[i]));
    __shared__ float red[256];
    red[tid] = acc;
    __syncthreads();
    for (int off = 128; off > 0; off >>= 1) {
        if (tid < off) red[tid] += red[tid + off];
        __syncthreads();
    }
    if (tid == 0)
        out[0] = red[0] / (float)N_SRC + sums[1] / (float)M_TGT;
}

extern "C" void kernel_launch(void* const* d_in, const int* in_sizes, int n_in,
                              void* d_out, int out_size, void* d_ws, size_t ws_size,
                              hipStream_t stream) {
    const float* src = (const float*)d_in[0];   // [N, D]
    const float* tgt = (const float*)d_in[1];   // [M, D]
    const float* psi = (const float*)d_in[2];   // [M]
    char* ws = (char*)d_ws;

    // zero l-accumulators + global sums (ws is 0xAA-poisoned each launch)
    hipMemsetAsync(ws + OFF_L, 0, 32768 + 64, stream);

    k1a_tgt<<<M_TGT / 32, 256, 0, stream>>>(tgt, psi, ws);
    k1b_src<<<256 + M_TGT / 256, 256, 0, stream>>>(src, psi, ws);
    k2_main<<<(N_SRC / 64) * QSPLIT, 256, 0, stream>>>(ws);
    k3_final<<<1, 256, 0, stream>>>(ws, (float*)d_out);
}

// Round 3
// 100.999 us; speedup vs baseline: 4.2805x; 1.1784x over previous
//
#include <hip/hip_runtime.h>
#include <math.h>
#include <stdint.h>

#define N_SRC 8192
#define M_TGT 16384
#define DDIM  64
#define REG_P 0.05f
#define LOG2E 1.44269504088896340736f
#define LN2   0.69314718055994530942f
#define QSPLIT 8          // column split: 128 rowblks x 8 = 1024 blocks for k2

typedef __attribute__((ext_vector_type(8))) short short8;
typedef __attribute__((ext_vector_type(4))) float f32x4;

// Workspace byte offsets
#define OFF_TGT  0u                          // staged tgt bf16, frag order: 2 MB
#define OFF_SRC  (2u << 20)                  // staged src bf16, frag order: 1 MB
#define OFF_SQT  (3u << 20)                  // sq_t[M] fp32: 64 KB
#define OFF_SQS  ((3u << 20) + 65536u)       // sq_s[N] fp32: 32 KB
#define OFF_PART ((3u << 20) + 98304u)       // k1 block partials float2[384]: 3 KB
#define OFF_L    ((3u << 20) + 102400u)      // l partials [QSPLIT][N] fp32: 256 KB

#define K1_BLOCKS 384                        // (1024 tgt tiles + 512 src tiles) / 4 waves

__device__ __forceinline__ unsigned short f2bf(float f) {   // RNE fp32->bf16
    unsigned u = __float_as_uint(f);
    u += 0x7fffu + ((u >> 16) & 1u);
    return (unsigned short)(u >> 16);
}

__device__ __forceinline__ float fast_exp2(float x) {
#if __has_builtin(__builtin_amdgcn_exp2f)
    return __builtin_amdgcn_exp2f(x);
#else
    return exp2f(x);
#endif
}

// k1: stage tgt+src to bf16 frag-order (lane-contiguous 1KB stores per wave),
// per-row sq norms, per-block partial sums of (sq_t, psi). No atomics.
__global__ __launch_bounds__(256) void k1_stage(const float* __restrict__ src,
                                                const float* __restrict__ tgt,
                                                const float* __restrict__ psi,
                                                char* __restrict__ ws) {
    const int tid  = threadIdx.x;
    const int wave = tid >> 6;
    const int lane = tid & 63;
    const int lo   = lane & 15;           // row within 16-row tile
    const int hi   = lane >> 4;           // 8-dim group within 32-dim K-half
    const int task = blockIdx.x * 4 + wave;   // 0..1535

    float sq_contrib = 0.f;   // this lane's share of sum(sq_t) (targets only)
    float ps_contrib = 0.f;   // this lane's share of sum(psi)

    if (task < 1024) {                    // tgt tile T = task
        const int T = task;
        const int j = T * 16 + lo;
        float sq = 0.f;
#pragma unroll
        for (int kk = 0; kk < 2; ++kk) {
            const float* p = tgt + (size_t)j * DDIM + kk * 32 + hi * 8;
            float4 v0 = ((const float4*)p)[0];
            float4 v1 = ((const float4*)p)[1];
            short8 pk;
            pk[0]=(short)f2bf(v0.x); pk[1]=(short)f2bf(v0.y); pk[2]=(short)f2bf(v0.z); pk[3]=(short)f2bf(v0.w);
            pk[4]=(short)f2bf(v1.x); pk[5]=(short)f2bf(v1.y); pk[6]=(short)f2bf(v1.z); pk[7]=(short)f2bf(v1.w);
            ((short8*)(ws + OFF_TGT))[(T * 2 + kk) * 64 + lane] = pk;
            sq += v0.x*v0.x + v0.y*v0.y + v0.z*v0.z + v0.w*v0.w
                + v1.x*v1.x + v1.y*v1.y + v1.z*v1.z + v1.w*v1.w;
        }
        float r = sq;
        r += __shfl_xor(r, 16); r += __shfl_xor(r, 32);   // sum over hi
        if (hi == 0) {
            ((float*)(ws + OFF_SQT))[j] = r;
            ps_contrib = psi[j];
        }
        sq_contrib = sq;
    } else {                              // src tile g = task - 1024
        const int g = task - 1024;
        const int i = g * 16 + lo;
        float sq = 0.f;
#pragma unroll
        for (int kk = 0; kk < 2; ++kk) {
            const float* p = src + (size_t)i * DDIM + kk * 32 + hi * 8;
            float4 v0 = ((const float4*)p)[0];
            float4 v1 = ((const float4*)p)[1];
            short8 pk;
            pk[0]=(short)f2bf(v0.x); pk[1]=(short)f2bf(v0.y); pk[2]=(short)f2bf(v0.z); pk[3]=(short)f2bf(v0.w);
            pk[4]=(short)f2bf(v1.x); pk[5]=(short)f2bf(v1.y); pk[6]=(short)f2bf(v1.z); pk[7]=(short)f2bf(v1.w);
            ((short8*)(ws + OFF_SRC))[(g * 2 + kk) * 64 + lane] = pk;
            sq += v0.x*v0.x + v0.y*v0.y + v0.z*v0.z + v0.w*v0.w
                + v1.x*v1.x + v1.y*v1.y + v1.z*v1.z + v1.w*v1.w;
        }
        float r = sq;
        r += __shfl_xor(r, 16); r += __shfl_xor(r, 32);
        if (hi == 0) ((float*)(ws + OFF_SQS))[i] = r;
    }

    // block partial: wave-reduce both values, then cross-wave via LDS
    float a = sq_contrib, b = ps_contrib;
#pragma unroll
    for (int off = 1; off < 64; off <<= 1) {
        a += __shfl_xor(a, off);
        b += __shfl_xor(b, off);
    }
    __shared__ float s_a[4], s_b[4];
    if (lane == 0) { s_a[wave] = a; s_b[wave] = b; }
    __syncthreads();
    if (tid == 0) {
        float2 out;
        out.x = s_a[0] + s_a[1] + s_a[2] + s_a[3];
        out.y = s_b[0] + s_b[1] + s_b[2] + s_b[3];
        ((float2*)(ws + OFF_PART))[blockIdx.x] = out;
    }
}

// k2: MFMA GEMM fused with sum-exp2, B fragments streamed from L2, no LDS
// staging, no barriers in the hot loop. 64 rows x 2048-col slice per block;
// each wave owns 512 cols (32 tiles) independently.
__global__ __launch_bounds__(256, 4) void k2_main(const float* __restrict__ psi,
                                                  char* __restrict__ ws) {
    const int tid    = threadIdx.x;
    const int lane   = tid & 63;
    const int w      = tid >> 6;
    const int rowblk = blockIdx.x >> 3;
    const int q      = blockIdx.x & (QSPLIT - 1);
    const int row0   = rowblk * 64;

    // sum of k1 block partials -> inv_cn (deterministic, in-register)
    const float2* __restrict__ part = (const float2*)(ws + OFF_PART);
    float ssq = 0.f;
#pragma unroll
    for (int k = 0; k < K1_BLOCKS / 64; ++k) ssq += part[k * 64 + lane].x;
#pragma unroll
    for (int off = 1; off < 64; off <<= 1) ssq += __shfl_xor(ssq, off);
    const float inv_cn = (float)M_TGT / ssq;
    const float c_psi  = (1.0f / REG_P) * LOG2E;     // psi scale (exp2 domain)
    const float c_sqt  = inv_cn * c_psi;             // sq_t scale
    const float alpha2 = 2.0f * c_sqt;               // cross-term scale

    // A fragments: 64 rows, resident all kernel
    const short8* __restrict__ srcst = (const short8*)(ws + OFF_SRC);
    short8 Af[4][2];
#pragma unroll
    for (int g = 0; g < 4; ++g)
#pragma unroll
        for (int kk = 0; kk < 2; ++kk)
            Af[g][kk] = srcst[((row0 >> 4) + g) * 128 + kk * 64 + lane];

    const short8* __restrict__ tgtst = (const short8*)(ws + OFF_TGT);
    const float*  __restrict__ sqt   = (const float*)(ws + OFF_SQT);

    const int T0    = (q * 2048 + w * 512) >> 4;   // first global col-tile
    const int jlane = (T0 << 4) + (lane & 15);     // bias col for this lane

    float lsum[4][4];
#pragma unroll
    for (int g = 0; g < 4; ++g)
#pragma unroll
        for (int r = 0; r < 4; ++r) lsum[g][r] = 0.f;

    // prefetch tile 0
    short8 B0n = tgtst[(T0 * 2 + 0) * 64 + lane];
    short8 B1n = tgtst[(T0 * 2 + 1) * 64 + lane];
    float  psn = psi[jlane];
    float  sqn = sqt[jlane];

    for (int t = 0; t < 32; ++t) {
        short8 B0 = B0n, B1 = B1n;
        float  ps = psn, sq = sqn;
        if (t < 31) {
            const int Tg = T0 + t + 1;
            B0n = tgtst[(Tg * 2 + 0) * 64 + lane];
            B1n = tgtst[(Tg * 2 + 1) * 64 + lane];
            psn = psi[jlane + (t + 1) * 16];
            sqn = sqt[jlane + (t + 1) * 16];
        }
        const float bias = ps * c_psi - sq * c_sqt;
        f32x4 acc[4];
#pragma unroll
        for (int g = 0; g < 4; ++g) {
            f32x4 a = {0.f, 0.f, 0.f, 0.f};
            a = __builtin_amdgcn_mfma_f32_16x16x32_bf16(Af[g][0], B0, a, 0, 0, 0);
            a = __builtin_amdgcn_mfma_f32_16x16x32_bf16(Af[g][1], B1, a, 0, 0, 0);
            acc[g] = a;
        }
#pragma unroll
        for (int g = 0; g < 4; ++g)
#pragma unroll
            for (int r = 0; r < 4; ++r)
                lsum[g][r] += fast_exp2(fmaf(alpha2, acc[g][r], bias));
    }

    // reduce over the 16 cols per row, combine the block's 4 waves via LDS
    __shared__ float s_l[4][64];
#pragma unroll
    for (int g = 0; g < 4; ++g)
#pragma unroll
        for (int r = 0; r < 4; ++r) {
            float v = lsum[g][r];
            v += __shfl_xor(v, 1); v += __shfl_xor(v, 2);
            v += __shfl_xor(v, 4); v += __shfl_xor(v, 8);
            if ((lane & 15) == 0)
                s_l[w][g * 16 + (lane >> 4) * 4 + r] = v;
        }
    __syncthreads();
    if (tid < 64) {
        float v = s_l[0][tid] + s_l[1][tid] + s_l[2][tid] + s_l[3][tid];
        ((float*)(ws + OFF_L))[q * N_SRC + row0 + tid] = v;   // per-q slice, no atomics
    }
}

// k3: combine q-slices, lse, final scalar. Single 1024-thread block.
__global__ __launch_bounds__(1024) void k3_final(const char* __restrict__ ws,
                                                 float* __restrict__ out) {
    const int tid  = threadIdx.x;
    const int lane = tid & 63;

    const float2* __restrict__ part = (const float2*)(ws + OFF_PART);
    float ssq = 0.f, spsi = 0.f;
#pragma unroll
    for (int k = 0; k < K1_BLOCKS / 64; ++k) {
        float2 p = part[k * 64 + lane];
        ssq += p.x; spsi += p.y;
    }
#pragma unroll
    for (int off = 1; off < 64; off <<= 1) {
        ssq  += __shfl_xor(ssq, off);
        spsi += __shfl_xor(spsi, off);
    }
    const float inv_cn = (float)M_TGT / ssq;

    const float* __restrict__ L   = (const float*)(ws + OFF_L);
    const float* __restrict__ sqs = (const float*)(ws + OFF_SQS);
    const float logM = logf((float)M_TGT);

    float acc = 0.f;
    for (int i = tid; i < N_SRC; i += 1024) {
        float lt = 0.f;
#pragma unroll
        for (int qq = 0; qq < QSPLIT; ++qq) lt += L[qq * N_SRC + i];
        const float A = -sqs[i] * inv_cn * (1.0f / REG_P) - logM;
        acc += -REG_P * (A + LN2 * __log2f(lt));
    }
    __shared__ float red[1024];
    red[tid] = acc;
    __syncthreads();
    for (int off = 512; off > 0; off >>= 1) {
        if (tid < off) red[tid] += red[tid + off];
        __syncthreads();
    }
    if (tid == 0)
        out[0] = red[0] / (float)N_SRC + spsi / (float)M_TGT;
}

extern "C" void kernel_launch(void* const* d_in, const int* in_sizes, int n_in,
                              void* d_out, int out_size, void* d_ws, size_t ws_size,
                              hipStream_t stream) {
    const float* src = (const float*)d_in[0];   // [N, D]
    const float* tgt = (const float*)d_in[1];   // [M, D]
    const float* psi = (const float*)d_in[2];   // [M]
    char* ws = (char*)d_ws;

    k1_stage<<<K1_BLOCKS, 256, 0, stream>>>(src, tgt, psi, ws);
    k2_main<<<(N_SRC / 64) * QSPLIT, 256, 0, stream>>>(psi, ws);
    k3_final<<<1, 1024, 0, stream>>>(ws, (float*)d_out);
}